// Round 6
// baseline (127.152 us; speedup 1.0000x reference)
//
#include <hip/hip_runtime.h>
#include <math.h>

#define NB 16
#define NA 8400
#define NG 50
#define TK 10
#define SELT 256
#define LP 11       // padded per-thread list stride in LDS (bank-conflict mitigation)
#define NCHUNK 33   // ceil(NA/256)
#define MCAP 512    // matched-list capacity per image

// padded counter layout (64-B line granularity within a 256-B block per image)
#define CTR_FG(b)  ((b)*64)        // nFg per image
#define CTR_M(b)   ((b)*64 + 16)   // nM per image
#define CTR_SD(b)  ((b)*64 + 32)   // select-done per image
#define CTR_FD     (16*64)         // global final-done

__device__ __forceinline__ float sigmoidf_(float x){ return 1.f/(1.f+expf(-x)); }
__device__ __forceinline__ float softplusf_(float x){ return log1pf(expf(-fabsf(x))) + fmaxf(x, 0.f); }
__device__ __forceinline__ float bce_(float x, float t){ return softplusf_(x) - x*t; }
__device__ __forceinline__ float sl1_(float d){
    const float B = 1.f/9.f;
    float a = fabsf(d);
    return a < B ? 0.5f*a*a/B : a - 0.5f*B;
}

__device__ __forceinline__ void anchor_geom(int a, int& lvl, int& hw, int& gx, int& gy, float& st){
    if (a < 6400){ lvl=0; hw=a;      gx=hw%80; gy=hw/80; st=8.f; }
    else if (a < 8000){ lvl=1; hw=a-6400; gx=hw%40; gy=hw/40; st=16.f; }
    else { lvl=2; hw=a-8000; gx=hw%20; gy=hw/20; st=32.f; }
}

__device__ __forceinline__ float giou_(float4 a, float4 b){
    float tlx = fmaxf(a.x,b.x), tly = fmaxf(a.y,b.y);
    float brx = fminf(a.z,b.z), bry = fminf(a.w,b.w);
    float iw = fmaxf(brx-tlx,0.f), ih = fmaxf(bry-tly,0.f);
    float inter = iw*ih;
    float aa = (a.z-a.x)*(a.w-a.y);
    float ab = (b.z-b.x)*(b.w-b.y);
    float uni = aa + ab - inter;
    float iou = inter / (uni + 1e-8f);
    float ctlx = fminf(a.x,b.x), ctly = fminf(a.y,b.y);
    float cbrx = fmaxf(a.z,b.z), cbry = fmaxf(a.w,b.w);
    float cw = fmaxf(cbrx-ctlx,0.f), ch = fmaxf(cbry-ctly,0.f);
    float ca = cw*ch;
    return iou - (ca - uni) / (ca + 1e-8f);
}

// ---------------- Kernel 1: decode + precompute + dense obj-loss + ordered fg compaction --------
// Channel loads issued FIRST (latency hiding under GT staging). All per-anchor state that
// later stages need is written COMPACTED at append time; dense state is one int4/anchor.
__global__ void __launch_bounds__(256) k_decode(
    const float* __restrict__ cls0, const float* __restrict__ reg0, const float* __restrict__ obj0, const float* __restrict__ lmk0,
    const float* __restrict__ cls1, const float* __restrict__ reg1, const float* __restrict__ obj1, const float* __restrict__ lmk1,
    const float* __restrict__ cls2, const float* __restrict__ reg2, const float* __restrict__ obj2, const float* __restrict__ lmk2,
    const float* __restrict__ gtb, const unsigned char* __restrict__ gtv_raw, unsigned char* __restrict__ gtv,
    int* __restrict__ fgList, int* __restrict__ posOf, int* __restrict__ ctr,
    float4* __restrict__ boxC, float4* __restrict__ metaC,
    float* __restrict__ ccPC, float* __restrict__ ccNC,
    float* __restrict__ lmkC, float2* __restrict__ ocC,
    int4* __restrict__ mstate, double* __restrict__ pObj)
{
    __shared__ float4 sgb[NG];
    __shared__ unsigned char sval[NG];
    __shared__ int sIsByte;
    __shared__ int swc[4];
    __shared__ int sbase;
    __shared__ double sred[256];
    int b = blockIdx.y;
    int tid = threadIdx.x;
    int a = blockIdx.x * 256 + tid;
    bool act = (a < NA);

    // ---- issue all anchor channel loads FIRST ----
    int lvl, hw, gx, gy; float st = 0.f;
    float rx=0.f, ry=0.f, rw=0.f, rh=0.f, cl=0.f, ob=0.f, lmv[10];
    #pragma unroll
    for (int k = 0; k < 10; k++) lmv[k] = 0.f;
    if (act){
        anchor_geom(a, lvl, hw, gx, gy, st);
        const float* cp = lvl==0?cls0:(lvl==1?cls1:cls2);
        const float* rp = lvl==0?reg0:(lvl==1?reg1:reg2);
        const float* op = lvl==0?obj0:(lvl==1?obj1:obj2);
        const float* lp = lvl==0?lmk0:(lvl==1?lmk1:lmk2);
        int HW = lvl==0?6400:(lvl==1?1600:400);
        rx = rp[(b*4+0)*HW+hw]; ry = rp[(b*4+1)*HW+hw];
        rw = rp[(b*4+2)*HW+hw]; rh = rp[(b*4+3)*HW+hw];
        cl = cp[b*HW+hw]; ob = op[b*HW+hw];
        #pragma unroll
        for (int k = 0; k < 10; k++) lmv[k] = lp[(b*10+k)*HW+hw];
    }

    // ---- GT staging + gt_valid layout normalize (overlaps loads in flight) ----
    if (tid == 0) sIsByte = 0;
    if (tid < NG){
        const float* gp = &gtb[(size_t)(b*NG+tid)*4];
        sgb[tid] = make_float4(gp[0], gp[1], gp[2], gp[3]);
    }
    __syncthreads();
    {
        int any = 0;
        for (int i = tid; i < NB*NG; i += 256) if ((i & 3) && gtv_raw[i]) any = 1;
        if (any) sIsByte = 1;          // benign race, all write 1
    }
    __syncthreads();
    if (tid < NG){
        unsigned char vv = sIsByte ? (gtv_raw[b*NG+tid] != 0) : (gtv_raw[4*(b*NG+tid)] != 0);
        sval[tid] = vv;
        if (blockIdx.x == 0) gtv[b*NG+tid] = vv;
    }
    __syncthreads();

    // ---- compute ----
    double so = 0.0;
    bool f = false;
    float4 bx; float ax=0.f, ay=0.f, r=0.f, abv=0.f, ccPv=0.f, ccNv=0.f;
    float lmc[10];
    if (act){
        int idx = b*NA + a;
        float xc = (rx + (float)gx) * st, yc = (ry + (float)gy) * st;
        float wd = expf(rw) * st, ht = expf(rh) * st;
        bx = make_float4(xc - 0.5f*wd, yc - 0.5f*ht, xc + 0.5f*wd, yc + 0.5f*ht);
        abv = (bx.z - bx.x) * (bx.w - bx.y);
        so = (double)softplusf_(ob);     // dense obj-loss term: bce(x,0) = softplus(x)
        float p = sqrtf(sigmoidf_(cl) * sigmoidf_(ob));
        ccPv = -fmaxf(logf(p), -100.f);
        ccNv = -fmaxf(logf(1.f - p), -100.f);
        #pragma unroll
        for (int k = 0; k < 5; k++){
            lmc[2*k]   = (lmv[2*k]   + (float)gx) * st;
            lmc[2*k+1] = (lmv[2*k+1] + (float)gy) * st;
        }
        mstate[idx] = make_int4(0, 0x7fffffff, 0, 0);   // cnt, first, piou(=0.f bits), pad
        ax = ((float)gx + 0.5f) * st; ay = ((float)gy + 0.5f) * st;
        r = 2.5f * st;
        for (int g = 0; g < NG; g++){
            if (!__ballot(!f)) break;    // whole wave fg -> done (f monotone)
            if (!sval[g]) continue;
            float4 gv = sgb[g];
            bool inb = fminf(fminf(ax-gv.x, gv.z-ax), fminf(ay-gv.y, gv.w-ay)) > 0.f;
            float cx = (gv.x+gv.z)*0.5f, cy = (gv.y+gv.w)*0.5f;
            bool inc = fminf(fminf(ax-(cx-r), (cx+r)-ax), fminf(ay-(cy-r), (cy+r)-ay)) > 0.f;
            f = f || inb || inc;
        }
    }

    // single block-level atomic; wave offsets reconstructed from LDS prefix
    unsigned long long m = __ballot(f);
    int wave = tid >> 6, lane = tid & 63;
    if (lane == 0) swc[wave] = __popcll(m);
    __syncthreads();
    if (tid == 0){
        int tot = swc[0] + swc[1] + swc[2] + swc[3];
        sbase = tot ? atomicAdd(&ctr[CTR_FG(b)], tot) : 0;
    }
    __syncthreads();
    if (f){
        int wbase = sbase;
        for (int w = 0; w < 4; w++) if (w < wave) wbase += swc[w];
        int pos = wbase + __popcll(m & ((1ull << lane) - 1ull));
        fgList[b*NA + pos] = a;
        posOf[b*NA + a] = pos;
        boxC[b*NA + pos] = bx;
        metaC[b*NA + pos] = make_float4(ax, ay, r, abv);
        ccPC[b*NA + pos] = ccPv;
        ccNC[b*NA + pos] = ccNv;
        ocC[b*NA + pos] = make_float2(ob, cl);
        #pragma unroll
        for (int k = 0; k < 10; k++) lmkC[(size_t)(b*NA + pos)*10 + k] = lmc[k];
    }

    // block reduction of dense obj loss (no extra global loads)
    sred[tid] = so;
    for (int off = 128; off >= 1; off >>= 1){
        __syncthreads();
        if (tid < off) sred[tid] += sred[tid+off];
    }
    if (tid == 0) pObj[b*NCHUNK + blockIdx.x] = sred[0];
}

// ---------------- Kernel 2: per-(b,g) dyn_k top-k + scatter + fused fg-loss + final ------------
__global__ void __launch_bounds__(SELT) k_select(
    const int* __restrict__ fgList, const int* __restrict__ posOf, int* __restrict__ ctr,
    const float4* __restrict__ boxC, const float4* __restrict__ metaC,
    const float* __restrict__ ccPC, const float* __restrict__ ccNC,
    const float* __restrict__ lmkC, const float2* __restrict__ ocC,
    int4* __restrict__ mstate, int* __restrict__ mList,
    const float* __restrict__ gtb, const int* __restrict__ gtl,
    const float* __restrict__ gtlm, const unsigned char* __restrict__ gtv,
    const double* __restrict__ pObj, double* __restrict__ partials, float* __restrict__ out)
{
    // aliased LDS: select phase {sIou 11264 | sK 22528}; finisher phase re-carves the same bytes
    __shared__ __align__(16) unsigned char smem[33792];
    __shared__ int sDk;
    __shared__ int sFin;
    __shared__ int sFin2;
    float* sIou = (float*)smem;
    unsigned long long* sK = (unsigned long long*)(smem + 11264);

    int bg = blockIdx.x;
    int b = bg / NG, g = bg - b*NG;
    int tid = threadIdx.x;
    bool gvalid = gtv[b*NG+g] != 0;

    if (gvalid){
        const float* gp = &gtb[(size_t)(b*NG+g)*4];
        float4 gb = make_float4(gp[0], gp[1], gp[2], gp[3]);
        bool lab0 = (gtl[b*NG+g] == 0);
        int nf = ctr[CTR_FG(b)];

        float ag = (gb.z - gb.x) * (gb.w - gb.y);
        float cx = (gb.x + gb.z) * 0.5f, cy = (gb.y + gb.w) * 0.5f;

        const float4* bC = boxC  + (size_t)b*NA;
        const float4* mC = metaC + (size_t)b*NA;
        const float*  cS = (lab0 ? ccPC : ccNC) + (size_t)b*NA;
        const int*    fL = fgList + (size_t)b*NA;

        float mi[TK]; unsigned long long mk[TK];
        #pragma unroll
        for (int k = 0; k < TK; k++){ mi[k] = 0.f; mk[k] = 0xFFFFFFFFFFFFFFFFull; }

        // software-pipelined scan
        int i = tid;
        float4 bxv, mt; float ccv; unsigned int ia;
        if (i < nf){ bxv = bC[i]; mt = mC[i]; ccv = cS[i]; ia = (unsigned int)fL[i]; }
        while (i < nf){
            int i2 = i + SELT;
            float4 bxv2, mt2; float ccv2; unsigned int ia2;
            if (i2 < nf){ bxv2 = bC[i2]; mt2 = mC[i2]; ccv2 = cS[i2]; ia2 = (unsigned int)fL[i2]; }
            float tlx = fmaxf(gb.x, bxv.x), tly = fmaxf(gb.y, bxv.y);
            float brx = fminf(gb.z, bxv.z), bry = fminf(gb.w, bxv.w);
            float iw = fmaxf(brx - tlx, 0.f), ih = fmaxf(bry - tly, 0.f);
            float inter = iw * ih;
            float im = inter / (ag + mt.w - inter + 1e-8f);
            float ax = mt.x, ay = mt.y, r = mt.z;
            bool inb = fminf(fminf(ax-gb.x, gb.z-ax), fminf(ay-gb.y, gb.w-ay)) > 0.f;
            bool inc = fminf(fminf(ax-(cx-r), (cx+r)-ax), fminf(ay-(cy-r), (cy+r)-ay)) > 0.f;
            float c = ccv - 3.f * logf(im + 1e-8f);
            if (!(inb && inc)) c += 1e5f;
            if (im > mi[TK-1]){
                float v = im;
                #pragma unroll
                for (int k = 0; k < TK; k++){
                    if (v > mi[k]){ float t = mi[k]; mi[k] = v; v = t; }
                }
            }
            unsigned int fb = __float_as_uint(c);
            unsigned int ck = fb ^ ((unsigned int)((int)fb >> 31) | 0x80000000u);
            unsigned long long key = ((unsigned long long)ck << 32) | ia;
            if (key < mk[TK-1]){
                unsigned long long kv = key;
                #pragma unroll
                for (int k = 0; k < TK; k++){
                    if (kv < mk[k]){ unsigned long long t = mk[k]; mk[k] = kv; kv = t; }
                }
            }
            i = i2; bxv = bxv2; mt = mt2; ccv = ccv2; ia = ia2;
        }

        #pragma unroll
        for (int k = 0; k < TK; k++){
            sIou[tid*LP+k] = mi[k];
            sK[tid*LP+k] = mk[k];
        }

        for (int off = SELT/2; off >= 1; off >>= 1){
            __syncthreads();
            if (tid < off){
                { // merge descending iou lists
                    float* Al = &sIou[tid*LP]; float* Bl = &sIou[(tid+off)*LP];
                    float r2[TK]; int ii = 0, jj = 0;
                    for (int k = 0; k < TK; k++){
                        bool ta = (jj >= TK) || (ii < TK && Al[ii] >= Bl[jj]);
                        r2[k] = ta ? Al[ii++] : Bl[jj++];
                    }
                    for (int k = 0; k < TK; k++) Al[k] = r2[k];
                }
                { // merge ascending u64 key lists
                    unsigned long long* Ak = &sK[tid*LP]; unsigned long long* Bk = &sK[(tid+off)*LP];
                    unsigned long long rk[TK]; int ii = 0, jj = 0;
                    for (int k = 0; k < TK; k++){
                        bool ta = (jj >= TK) || (ii < TK && Ak[ii] <= Bk[jj]);
                        rk[k] = ta ? Ak[ii++] : Bk[jj++];
                    }
                    for (int k = 0; k < TK; k++) Ak[k] = rk[k];
                }
            }
        }
        __syncthreads();
        if (tid == 0){
            float s = 0.f;
            for (int k = 0; k < TK; k++) s += sIou[k];
            int dk = (int)s;
            if (dk < 1) dk = 1;
            if (dk > TK) dk = TK;
            sDk = dk;
        }
        __syncthreads();
        int dk = sDk;
        // matched set = first dk entries of the sorted key list
        if (tid < dk){
            unsigned long long kk = sK[tid];
            unsigned int a = (unsigned int)(kk & 0xFFFFFFFFull);
            if (a < (unsigned int)NA){      // skip sentinels when nf < dk
                int pos = posOf[b*NA + (int)a];
                int* mp = (int*)&mstate[b*NA + (int)a];
                int old = atomicAdd(mp, 1);
                if (old == 0){              // first match appends to compact matched list
                    int p = atomicAdd(&ctr[CTR_M(b)], 1);
                    mList[b*MCAP + p] = (int)a;
                }
                atomicMin(mp + 1, g);
                float4 bxv = boxC[b*NA + pos];
                float4 mt = metaC[b*NA + pos];
                float tlx = fmaxf(gb.x, bxv.x), tly = fmaxf(gb.y, bxv.y);
                float brx = fminf(gb.z, bxv.z), bry = fminf(gb.w, bxv.w);
                float iw = fmaxf(brx - tlx, 0.f), ih = fmaxf(bry - tly, 0.f);
                float inter = iw * ih;
                float im = inter / (ag + mt.w - inter + 1e-8f);
                atomicAdd((float*)(mp + 2), im);   // single contributor when cnt==1
            }
        }
    }

    // ---- per-image completion: 50th block of image b runs the fg-loss inline ----
    __syncthreads();            // drain this block's scatter memory ops
    __threadfence();
    if (tid == 0) sFin = (atomicAdd(&ctr[CTR_SD(b)], 1) == NG - 1);
    __syncthreads();
    if (!sFin) return;
    __threadfence();

    // re-carve LDS for the finisher
    float4* fgb = (float4*)smem;                       //   800 B
    float*  flm = (float*)(smem + 800);                //  2000 B
    int*    flab = (int*)(smem + 2800);                //   200 B
    unsigned char* fval = smem + 3000;                 //    50 B
    double* sred = (double*)(smem + 3056);             // 12288 B
    double* sf = (double*)(smem + 15344);              //   640 B (16×5)

    if (tid < NG){
        const float* gp = &gtb[(size_t)(b*NG+tid)*4];
        fgb[tid] = make_float4(gp[0], gp[1], gp[2], gp[3]);
        flab[tid] = gtl[b*NG+tid];
        fval[tid] = gtv[b*NG+tid];
    }
    for (int i = tid; i < NG*10; i += 256) flm[i] = gtlm[(size_t)b*NG*10 + i];
    __syncthreads();

    int n = atomicAdd(&ctr[CTR_M(b)], 0);    // coherent read of nM
    double lo = 0, lc = 0, li = 0, lnum = 0, lden = 0, nfg = 0;

    for (int i = tid; i < n; i += 256){
        int a = mList[b*MCAP + i];
        int pos = posOf[b*NA + a];
        int4 ms = mstate[b*NA + a];
        float4 bx = boxC[b*NA + pos];
        float4 mt = metaC[b*NA + pos];
        float2 oc = ocC[b*NA + pos];
        float pious; int m;
        if (ms.x == 1){ m = ms.y; pious = __int_as_float(ms.z); }
        else {
            // conflict: argmin cost over ALL GTs (reference's keep = argmin, first-min on ties)
            float ax = mt.x, ay = mt.y, r = mt.z, ab = mt.w;
            float cp = ccPC[b*NA + pos], cn = ccNC[b*NA + pos];
            float bestC = INFINITY, bestIou = 0.f; int bestG = 0;
            for (int g2 = 0; g2 < NG; g2++){
                float4 gbv = fgb[g2];
                int valid = fval[g2];
                float tlx = fmaxf(gbv.x, bx.x), tly = fmaxf(gbv.y, bx.y);
                float brx = fminf(gbv.z, bx.z), bry = fminf(gbv.w, bx.w);
                float iw = fmaxf(brx - tlx, 0.f), ih = fmaxf(bry - tly, 0.f);
                float inter = iw * ih;
                float agv = (gbv.z - gbv.x) * (gbv.w - gbv.y);
                float im = inter / (agv + ab - inter + 1e-8f);
                bool inb = (fminf(fminf(ax-gbv.x, gbv.z-ax), fminf(ay-gbv.y, gbv.w-ay)) > 0.f) && valid;
                float cxg = (gbv.x + gbv.z) * 0.5f, cyg = (gbv.y + gbv.w) * 0.5f;
                bool inc = (fminf(fminf(ax-(cxg-r), (cxg+r)-ax), fminf(ay-(cyg-r), (cyg+r)-ay)) > 0.f) && valid;
                float cc = (flab[g2] == 0) ? cp : cn;
                float c = cc - 3.f * logf(im + 1e-8f);
                if (!(inb && inc)) c += 1e5f;
                if (!valid) c += 1e9f;
                if (c < bestC){ bestC = c; bestG = g2; bestIou = im; }
            }
            m = bestG; pious = bestIou;
        }
        lo += (double)(-oc.x);               // bce(x,1) - bce(x,0) = -x  (fg correction)
        float tgt = (flab[m] == 0) ? pious : 0.f;
        lc += (double)bce_(oc.y, tgt);
        li += (double)(1.f - giou_(bx, fgb[m]));
        #pragma unroll
        for (int k = 0; k < 5; k++){
            float tx = flm[m*10 + 2*k];
            float ty = flm[m*10 + 2*k + 1];
            if (tx >= 0.f && ty >= 0.f){
                lnum += (double)(sl1_(lmkC[(size_t)(b*NA+pos)*10 + 2*k] - tx)
                               + sl1_(lmkC[(size_t)(b*NA+pos)*10 + 2*k + 1] - ty));
                lden += 1.0;
            }
        }
        nfg += 1.0;
    }

    sred[0*256+tid] = lo; sred[1*256+tid] = lc; sred[2*256+tid] = li;
    sred[3*256+tid] = lnum; sred[4*256+tid] = lden; sred[5*256+tid] = nfg;
    for (int off = 128; off >= 1; off >>= 1){
        __syncthreads();
        if (tid < off){
            #pragma unroll
            for (int q = 0; q < 6; q++) sred[q*256+tid] += sred[q*256+tid+off];
        }
    }
    if (tid == 0){
        #pragma unroll
        for (int q = 0; q < 6; q++) partials[b*6 + q] = sred[q*256];
    }

    // ---- global final combine: last image-finisher does it ----
    __threadfence();
    if (tid == 0) sFin2 = (atomicAdd(&ctr[CTR_FD], 1) == NB - 1);
    __syncthreads();
    if (!sFin2) return;
    __threadfence();

    if (tid < NB){
        double flo = 0;
        for (int ch = 0; ch < NCHUNK; ch++) flo += pObj[tid*NCHUNK + ch];
        const double* p = &partials[tid*6];
        flo += p[0];
        sf[tid*5+0] = flo; sf[tid*5+1] = p[1]; sf[tid*5+2] = p[2];
        sf[tid*5+3] = p[3] / fmax(p[4], 1.0); sf[tid*5+4] = p[5];
    }
    __syncthreads();
    if (tid == 0){
        double flo = 0, flc = 0, fli = 0, fll = 0, fnfg = 0;
        for (int bb = 0; bb < NB; bb++){
            flo += sf[bb*5+0]; flc += sf[bb*5+1]; fli += sf[bb*5+2];
            fll += sf[bb*5+3]; fnfg += sf[bb*5+4];
        }
        double nf2 = fmax(fnfg, 1.0);
        double liou = 5.0 * fli / nf2;
        double lobj = 1.0 * flo / nf2;
        double lcls = 1.0 * flc / nf2;
        double llmk = 5.0 * fll / nf2;
        out[0] = (float)(liou + lobj + lcls + llmk);
        out[1] = (float)liou;
        out[2] = (float)lobj;
        out[3] = (float)lcls;
        out[4] = (float)llmk;
    }
}

extern "C" void kernel_launch(void* const* d_in, const int* in_sizes, int n_in,
                              void* d_out, int out_size, void* d_ws, size_t ws_size,
                              hipStream_t stream) {
    const float* cls0 = (const float*)d_in[0];
    const float* reg0 = (const float*)d_in[1];
    const float* obj0 = (const float*)d_in[2];
    const float* lmk0 = (const float*)d_in[3];
    const float* cls1 = (const float*)d_in[4];
    const float* reg1 = (const float*)d_in[5];
    const float* obj1 = (const float*)d_in[6];
    const float* lmk1 = (const float*)d_in[7];
    const float* cls2 = (const float*)d_in[8];
    const float* reg2 = (const float*)d_in[9];
    const float* obj2 = (const float*)d_in[10];
    const float* lmk2 = (const float*)d_in[11];
    const float* gtb  = (const float*)d_in[12];
    const float* gtlm = (const float*)d_in[13];
    const int*   gtl  = (const int*)d_in[14];
    const unsigned char* gtv_raw = (const unsigned char*)d_in[15];
    float* out = (float*)d_out;

    char* ws = (char*)d_ws;
    size_t off = 0;
    float4* boxC  = (float4*)(ws + off); off += (size_t)NB*NA*sizeof(float4);
    float4* metaC = (float4*)(ws + off); off += (size_t)NB*NA*sizeof(float4);
    int4* mstate  = (int4*)(ws + off);   off += (size_t)NB*NA*sizeof(int4);
    float* lmkC = (float*)(ws + off); off += (size_t)NB*NA*10*sizeof(float);
    float2* ocC = (float2*)(ws + off); off += (size_t)NB*NA*sizeof(float2);
    float* ccPC = (float*)(ws + off); off += (size_t)NB*NA*sizeof(float);
    float* ccNC = (float*)(ws + off); off += (size_t)NB*NA*sizeof(float);
    int* fgList = (int*)(ws + off);   off += (size_t)NB*NA*sizeof(int);
    int* posOf  = (int*)(ws + off);   off += (size_t)NB*NA*sizeof(int);
    int* mList  = (int*)(ws + off);   off += (size_t)NB*MCAP*sizeof(int);
    int* ctr    = (int*)(ws + off);   off += (size_t)8192;
    double* pObj = (double*)(ws + off); off += (size_t)NB*NCHUNK*sizeof(double);
    double* partials = (double*)(ws + off); off += (size_t)NB*6*sizeof(double);
    unsigned char* gtv = (unsigned char*)(ws + off); off += (size_t)NB*NG;

    hipMemsetAsync(ctr, 0, 8192, stream);

    dim3 grdA(NCHUNK, NB);
    k_decode<<<grdA, dim3(256), 0, stream>>>(cls0, reg0, obj0, lmk0, cls1, reg1, obj1, lmk1,
                                             cls2, reg2, obj2, lmk2, gtb, gtv_raw, gtv,
                                             fgList, posOf, ctr, boxC, metaC, ccPC, ccNC,
                                             lmkC, ocC, mstate, pObj);

    k_select<<<dim3(NB*NG), dim3(SELT), 0, stream>>>(fgList, posOf, ctr, boxC, metaC, ccPC, ccNC,
                                                     lmkC, ocC, mstate, mList,
                                                     gtb, gtl, gtlm, gtv, pObj, partials, out);
}

// Round 7
// 76.198 us; speedup vs baseline: 1.6687x; 1.6687x over previous
//
#include <hip/hip_runtime.h>
#include <math.h>

#define NB 16
#define NA 8400
#define NG 50
#define TK 10
#define SELT 256
#define LP 11       // padded per-thread list stride in LDS (bank-conflict mitigation)
#define NCHUNK 33   // ceil(NA/256)
#define FGB 2       // fg-loss blocks per image
#define MCAP 512    // matched-list capacity per image

// padded counter layout (64-B line granularity within a 256-B block per image)
#define CTR_FG(b)  ((b)*64)        // nFg per image
#define CTR_M(b)   ((b)*64 + 16)   // nM per image
#define CTR_FD     (16*64)         // global final-done

__device__ __forceinline__ float sigmoidf_(float x){ return 1.f/(1.f+expf(-x)); }
__device__ __forceinline__ float softplusf_(float x){ return log1pf(expf(-fabsf(x))) + fmaxf(x, 0.f); }
__device__ __forceinline__ float bce_(float x, float t){ return softplusf_(x) - x*t; }
__device__ __forceinline__ float sl1_(float d){
    const float B = 1.f/9.f;
    float a = fabsf(d);
    return a < B ? 0.5f*a*a/B : a - 0.5f*B;
}

__device__ __forceinline__ void anchor_geom(int a, int& lvl, int& hw, int& gx, int& gy, float& st){
    if (a < 6400){ lvl=0; hw=a;      gx=hw%80; gy=hw/80; st=8.f; }
    else if (a < 8000){ lvl=1; hw=a-6400; gx=hw%40; gy=hw/40; st=16.f; }
    else { lvl=2; hw=a-8000; gx=hw%20; gy=hw/20; st=32.f; }
}

__device__ __forceinline__ float giou_(float4 a, float4 b){
    float tlx = fmaxf(a.x,b.x), tly = fmaxf(a.y,b.y);
    float brx = fminf(a.z,b.z), bry = fminf(a.w,b.w);
    float iw = fmaxf(brx-tlx,0.f), ih = fmaxf(bry-tly,0.f);
    float inter = iw*ih;
    float aa = (a.z-a.x)*(a.w-a.y);
    float ab = (b.z-b.x)*(b.w-b.y);
    float uni = aa + ab - inter;
    float iou = inter / (uni + 1e-8f);
    float ctlx = fminf(a.x,b.x), ctly = fminf(a.y,b.y);
    float cbrx = fmaxf(a.z,b.z), cbry = fmaxf(a.w,b.w);
    float cw = fmaxf(cbrx-ctlx,0.f), ch = fmaxf(cbry-ctly,0.f);
    float ca = cw*ch;
    return iou - (ca - uni) / (ca + 1e-8f);
}

// ---------------- Kernel 1: decode + precompute + dense obj-loss + ordered fg compaction --------
// Channel loads issued FIRST (latency hiding under GT staging). All per-anchor state that
// later stages need is written COMPACTED at append time; dense state is one int4/anchor.
__global__ void __launch_bounds__(256) k_decode(
    const float* __restrict__ cls0, const float* __restrict__ reg0, const float* __restrict__ obj0, const float* __restrict__ lmk0,
    const float* __restrict__ cls1, const float* __restrict__ reg1, const float* __restrict__ obj1, const float* __restrict__ lmk1,
    const float* __restrict__ cls2, const float* __restrict__ reg2, const float* __restrict__ obj2, const float* __restrict__ lmk2,
    const float* __restrict__ gtb, const unsigned char* __restrict__ gtv_raw, unsigned char* __restrict__ gtv,
    int* __restrict__ fgList, int* __restrict__ posOf, int* __restrict__ ctr,
    float4* __restrict__ boxC, float4* __restrict__ metaC,
    float* __restrict__ ccPC, float* __restrict__ ccNC,
    float* __restrict__ lmkC, float2* __restrict__ ocC,
    int4* __restrict__ mstate, double* __restrict__ pObj)
{
    __shared__ float4 sgb[NG];
    __shared__ unsigned char sval[NG];
    __shared__ int sIsByte;
    __shared__ int swc[4];
    __shared__ int sbase;
    __shared__ double sred[256];
    int b = blockIdx.y;
    int tid = threadIdx.x;
    int a = blockIdx.x * 256 + tid;
    bool act = (a < NA);

    // ---- issue all anchor channel loads FIRST ----
    int lvl, hw, gx, gy; float st = 0.f;
    float rx=0.f, ry=0.f, rw=0.f, rh=0.f, cl=0.f, ob=0.f, lmv[10];
    #pragma unroll
    for (int k = 0; k < 10; k++) lmv[k] = 0.f;
    if (act){
        anchor_geom(a, lvl, hw, gx, gy, st);
        const float* cp = lvl==0?cls0:(lvl==1?cls1:cls2);
        const float* rp = lvl==0?reg0:(lvl==1?reg1:reg2);
        const float* op = lvl==0?obj0:(lvl==1?obj1:obj2);
        const float* lp = lvl==0?lmk0:(lvl==1?lmk1:lmk2);
        int HW = lvl==0?6400:(lvl==1?1600:400);
        rx = rp[(b*4+0)*HW+hw]; ry = rp[(b*4+1)*HW+hw];
        rw = rp[(b*4+2)*HW+hw]; rh = rp[(b*4+3)*HW+hw];
        cl = cp[b*HW+hw]; ob = op[b*HW+hw];
        #pragma unroll
        for (int k = 0; k < 10; k++) lmv[k] = lp[(b*10+k)*HW+hw];
    }

    // ---- GT staging + gt_valid layout normalize (overlaps loads in flight) ----
    if (tid == 0) sIsByte = 0;
    if (tid < NG){
        const float* gp = &gtb[(size_t)(b*NG+tid)*4];
        sgb[tid] = make_float4(gp[0], gp[1], gp[2], gp[3]);
    }
    __syncthreads();
    {
        int any = 0;
        for (int i = tid; i < NB*NG; i += 256) if ((i & 3) && gtv_raw[i]) any = 1;
        if (any) sIsByte = 1;          // benign race, all write 1
    }
    __syncthreads();
    if (tid < NG){
        unsigned char vv = sIsByte ? (gtv_raw[b*NG+tid] != 0) : (gtv_raw[4*(b*NG+tid)] != 0);
        sval[tid] = vv;
        if (blockIdx.x == 0) gtv[b*NG+tid] = vv;
    }
    __syncthreads();

    // ---- compute ----
    double so = 0.0;
    bool f = false;
    float4 bx; float ax=0.f, ay=0.f, r=0.f, abv=0.f, ccPv=0.f, ccNv=0.f;
    float lmc[10];
    if (act){
        int idx = b*NA + a;
        float xc = (rx + (float)gx) * st, yc = (ry + (float)gy) * st;
        float wd = expf(rw) * st, ht = expf(rh) * st;
        bx = make_float4(xc - 0.5f*wd, yc - 0.5f*ht, xc + 0.5f*wd, yc + 0.5f*ht);
        abv = (bx.z - bx.x) * (bx.w - bx.y);
        so = (double)softplusf_(ob);     // dense obj-loss term: bce(x,0) = softplus(x)
        float p = sqrtf(sigmoidf_(cl) * sigmoidf_(ob));
        ccPv = -fmaxf(logf(p), -100.f);
        ccNv = -fmaxf(logf(1.f - p), -100.f);
        #pragma unroll
        for (int k = 0; k < 5; k++){
            lmc[2*k]   = (lmv[2*k]   + (float)gx) * st;
            lmc[2*k+1] = (lmv[2*k+1] + (float)gy) * st;
        }
        mstate[idx] = make_int4(0, 0x7fffffff, 0, 0);   // cnt, first, piou(=0.f bits), pad
        ax = ((float)gx + 0.5f) * st; ay = ((float)gy + 0.5f) * st;
        r = 2.5f * st;
        for (int g = 0; g < NG; g++){
            if (!__ballot(!f)) break;    // whole wave fg -> done (f monotone)
            if (!sval[g]) continue;
            float4 gv = sgb[g];
            bool inb = fminf(fminf(ax-gv.x, gv.z-ax), fminf(ay-gv.y, gv.w-ay)) > 0.f;
            float cx = (gv.x+gv.z)*0.5f, cy = (gv.y+gv.w)*0.5f;
            bool inc = fminf(fminf(ax-(cx-r), (cx+r)-ax), fminf(ay-(cy-r), (cy+r)-ay)) > 0.f;
            f = f || inb || inc;
        }
    }

    // single block-level atomic; wave offsets reconstructed from LDS prefix
    unsigned long long m = __ballot(f);
    int wave = tid >> 6, lane = tid & 63;
    if (lane == 0) swc[wave] = __popcll(m);
    __syncthreads();
    if (tid == 0){
        int tot = swc[0] + swc[1] + swc[2] + swc[3];
        sbase = tot ? atomicAdd(&ctr[CTR_FG(b)], tot) : 0;
    }
    __syncthreads();
    if (f){
        int wbase = sbase;
        for (int w = 0; w < 4; w++) if (w < wave) wbase += swc[w];
        int pos = wbase + __popcll(m & ((1ull << lane) - 1ull));
        fgList[b*NA + pos] = a;
        posOf[b*NA + a] = pos;
        boxC[b*NA + pos] = bx;
        metaC[b*NA + pos] = make_float4(ax, ay, r, abv);
        ccPC[b*NA + pos] = ccPv;
        ccNC[b*NA + pos] = ccNv;
        ocC[b*NA + pos] = make_float2(ob, cl);
        #pragma unroll
        for (int k = 0; k < 10; k++) lmkC[(size_t)(b*NA + pos)*10 + k] = lmc[k];
    }

    // block reduction of dense obj loss (no extra global loads)
    sred[tid] = so;
    for (int off = 128; off >= 1; off >>= 1){
        __syncthreads();
        if (tid < off) sred[tid] += sred[tid+off];
    }
    if (tid == 0) pObj[b*NCHUNK + blockIdx.x] = sred[0];
}

// ---------------- Kernel 2: per-(b,g) dyn_k top-k over compacted fg AoS; scatter matches --------
// No device fences here (round-6 lesson: fences in 800 blocks thrash XCD L2s).
__global__ void __launch_bounds__(SELT) k_select(
    const int* __restrict__ fgList, const int* __restrict__ posOf, int* __restrict__ ctr,
    const float4* __restrict__ boxC, const float4* __restrict__ metaC,
    const float* __restrict__ ccPC, const float* __restrict__ ccNC,
    const float* __restrict__ gtb, const int* __restrict__ gtl, const unsigned char* __restrict__ gtv,
    int4* __restrict__ mstate, int* __restrict__ mList)
{
    int bg = blockIdx.x;
    int b = bg / NG, g = bg - b*NG;
    if (!gtv[b*NG+g]) return;      // uniform for the block; invalid GT matches nothing
    int tid = threadIdx.x;

    __shared__ float sIou[SELT*LP];
    __shared__ unsigned long long sK[SELT*LP];
    __shared__ int sDk;

    const float* gp = &gtb[(size_t)(b*NG+g)*4];
    float4 gb = make_float4(gp[0], gp[1], gp[2], gp[3]);
    bool lab0 = (gtl[b*NG+g] == 0);
    int nf = ctr[CTR_FG(b)];

    // hoisted GT-derived terms
    float ag = (gb.z - gb.x) * (gb.w - gb.y);
    float cx = (gb.x + gb.z) * 0.5f, cy = (gb.y + gb.w) * 0.5f;

    const float4* bC = boxC  + (size_t)b*NA;
    const float4* mC = metaC + (size_t)b*NA;
    const float*  cS = (lab0 ? ccPC : ccNC) + (size_t)b*NA;
    const int*    fL = fgList + (size_t)b*NA;

    // iou sentinel 0.f == reference's zero rows; key sentinel = all-ones (> any real key)
    float mi[TK]; unsigned long long mk[TK];
    #pragma unroll
    for (int k = 0; k < TK; k++){ mi[k] = 0.f; mk[k] = 0xFFFFFFFFFFFFFFFFull; }

    // software-pipelined scan: issue iteration i+1's loads before processing i
    int i = tid;
    float4 bxv, mt; float ccv; unsigned int ia;
    if (i < nf){ bxv = bC[i]; mt = mC[i]; ccv = cS[i]; ia = (unsigned int)fL[i]; }
    while (i < nf){
        int i2 = i + SELT;
        float4 bxv2, mt2; float ccv2; unsigned int ia2;
        if (i2 < nf){ bxv2 = bC[i2]; mt2 = mC[i2]; ccv2 = cS[i2]; ia2 = (unsigned int)fL[i2]; }
        float tlx = fmaxf(gb.x, bxv.x), tly = fmaxf(gb.y, bxv.y);
        float brx = fminf(gb.z, bxv.z), bry = fminf(gb.w, bxv.w);
        float iw = fmaxf(brx - tlx, 0.f), ih = fmaxf(bry - tly, 0.f);
        float inter = iw * ih;
        float im = inter / (ag + mt.w - inter + 1e-8f);
        float ax = mt.x, ay = mt.y, r = mt.z;
        bool inb = fminf(fminf(ax-gb.x, gb.z-ax), fminf(ay-gb.y, gb.w-ay)) > 0.f;
        bool inc = fminf(fminf(ax-(cx-r), (cx+r)-ax), fminf(ay-(cy-r), (cy+r)-ay)) > 0.f;
        float c = ccv - 3.f * logf(im + 1e-8f);
        if (!(inb && inc)) c += 1e5f;
        if (im > mi[TK-1]){
            float v = im;
            #pragma unroll
            for (int k = 0; k < TK; k++){
                if (v > mi[k]){ float t = mi[k]; mi[k] = v; v = t; }
            }
        }
        unsigned int fb = __float_as_uint(c);
        unsigned int ck = fb ^ ((unsigned int)((int)fb >> 31) | 0x80000000u);
        unsigned long long key = ((unsigned long long)ck << 32) | ia;
        if (key < mk[TK-1]){
            unsigned long long kv = key;
            #pragma unroll
            for (int k = 0; k < TK; k++){
                if (kv < mk[k]){ unsigned long long t = mk[k]; mk[k] = kv; kv = t; }
            }
        }
        i = i2; bxv = bxv2; mt = mt2; ccv = ccv2; ia = ia2;
    }

    #pragma unroll
    for (int k = 0; k < TK; k++){
        sIou[tid*LP+k] = mi[k];
        sK[tid*LP+k] = mk[k];
    }

    for (int off = SELT/2; off >= 1; off >>= 1){
        __syncthreads();
        if (tid < off){
            { // merge descending iou lists
                float* Al = &sIou[tid*LP]; float* Bl = &sIou[(tid+off)*LP];
                float r2[TK]; int ii = 0, jj = 0;
                for (int k = 0; k < TK; k++){
                    bool ta = (jj >= TK) || (ii < TK && Al[ii] >= Bl[jj]);
                    r2[k] = ta ? Al[ii++] : Bl[jj++];
                }
                for (int k = 0; k < TK; k++) Al[k] = r2[k];
            }
            { // merge ascending u64 key lists
                unsigned long long* Ak = &sK[tid*LP]; unsigned long long* Bk = &sK[(tid+off)*LP];
                unsigned long long rk[TK]; int ii = 0, jj = 0;
                for (int k = 0; k < TK; k++){
                    bool ta = (jj >= TK) || (ii < TK && Ak[ii] <= Bk[jj]);
                    rk[k] = ta ? Ak[ii++] : Bk[jj++];
                }
                for (int k = 0; k < TK; k++) Ak[k] = rk[k];
            }
        }
    }
    __syncthreads();
    if (tid == 0){
        float s = 0.f;
        for (int k = 0; k < TK; k++) s += sIou[k];
        int dk = (int)s;
        if (dk < 1) dk = 1;
        if (dk > TK) dk = TK;
        sDk = dk;
    }
    __syncthreads();
    int dk = sDk;
    // matched set = first dk entries of the sorted key list
    if (tid < dk){
        unsigned long long kk = sK[tid];
        unsigned int a = (unsigned int)(kk & 0xFFFFFFFFull);
        if (a < (unsigned int)NA){      // skip sentinels when nf < dk
            int pos = posOf[b*NA + (int)a];
            int* mp = (int*)&mstate[b*NA + (int)a];
            int old = atomicAdd(mp, 1);
            if (old == 0){              // first match appends to compact matched list
                int p = atomicAdd(&ctr[CTR_M(b)], 1);
                mList[b*MCAP + p] = (int)a;
            }
            atomicMin(mp + 1, g);
            float4 bxv = boxC[b*NA + pos];
            float4 mt = metaC[b*NA + pos];
            float tlx = fmaxf(gb.x, bxv.x), tly = fmaxf(gb.y, bxv.y);
            float brx = fminf(gb.z, bxv.z), bry = fminf(gb.w, bxv.w);
            float iw = fmaxf(brx - tlx, 0.f), ih = fmaxf(bry - tly, 0.f);
            float inter = iw * ih;
            float im = inter / (ag + mt.w - inter + 1e-8f);
            atomicAdd((float*)(mp + 2), im);   // single contributor when cnt==1
        }
    }
}

// ---------------- Kernel 3: fg-only losses over compacted arrays + fused final combine ---------
__global__ void __launch_bounds__(256) k_fg_loss(
    const float4* __restrict__ boxC, const float4* __restrict__ metaC,
    const float* __restrict__ ccPC, const float* __restrict__ ccNC,
    const float* __restrict__ lmkC, const float2* __restrict__ ocC,
    const int* __restrict__ posOf, const int4* __restrict__ mstate,
    const int* __restrict__ mList, int* __restrict__ ctr,
    const float* __restrict__ gtb, const float* __restrict__ gtlm, const int* __restrict__ gtl,
    const unsigned char* __restrict__ gtv, double* __restrict__ partials,
    const double* __restrict__ pObj, float* __restrict__ out)
{
    __shared__ float4 sgb[NG];
    __shared__ int slab[NG];
    __shared__ unsigned char sval[NG];
    __shared__ float slmk[NG*10];
    int b = blockIdx.y;
    int tid = threadIdx.x;
    if (tid < NG){
        const float* gp = &gtb[(size_t)(b*NG+tid)*4];
        sgb[tid] = make_float4(gp[0], gp[1], gp[2], gp[3]);
        slab[tid] = gtl[b*NG+tid];
        sval[tid] = gtv[b*NG+tid];
    }
    for (int i = tid; i < NG*10; i += 256) slmk[i] = gtlm[(size_t)b*NG*10 + i];
    __syncthreads();

    int n = ctr[CTR_M(b)];
    double lo = 0, lc = 0, li = 0, lnum = 0, lden = 0, nfg = 0;

    for (int i = blockIdx.x*256 + tid; i < n; i += FGB*256){
        int a = mList[b*MCAP + i];
        int pos = posOf[b*NA + a];
        int4 ms = mstate[b*NA + a];
        float4 bx = boxC[b*NA + pos];
        float4 mt = metaC[b*NA + pos];
        float2 oc = ocC[b*NA + pos];
        float pious; int m;
        if (ms.x == 1){ m = ms.y; pious = __int_as_float(ms.z); }
        else {
            // conflict: argmin cost over ALL GTs (reference's keep = argmin, first-min on ties)
            float ax = mt.x, ay = mt.y, r = mt.z, ab = mt.w;
            float cp = ccPC[b*NA + pos], cn = ccNC[b*NA + pos];
            float bestC = INFINITY, bestIou = 0.f; int bestG = 0;
            for (int g = 0; g < NG; g++){
                float4 gbv = sgb[g];
                int valid = sval[g];
                float tlx = fmaxf(gbv.x, bx.x), tly = fmaxf(gbv.y, bx.y);
                float brx = fminf(gbv.z, bx.z), bry = fminf(gbv.w, bx.w);
                float iw = fmaxf(brx - tlx, 0.f), ih = fmaxf(bry - tly, 0.f);
                float inter = iw * ih;
                float agv = (gbv.z - gbv.x) * (gbv.w - gbv.y);
                float im = inter / (agv + ab - inter + 1e-8f);
                bool inb = (fminf(fminf(ax-gbv.x, gbv.z-ax), fminf(ay-gbv.y, gbv.w-ay)) > 0.f) && valid;
                float cxg = (gbv.x + gbv.z) * 0.5f, cyg = (gbv.y + gbv.w) * 0.5f;
                bool inc = (fminf(fminf(ax-(cxg-r), (cxg+r)-ax), fminf(ay-(cyg-r), (cyg+r)-ay)) > 0.f) && valid;
                float cc = (slab[g] == 0) ? cp : cn;
                float c = cc - 3.f * logf(im + 1e-8f);
                if (!(inb && inc)) c += 1e5f;
                if (!valid) c += 1e9f;
                if (c < bestC){ bestC = c; bestG = g; bestIou = im; }
            }
            m = bestG; pious = bestIou;
        }
        lo += (double)(-oc.x);               // bce(x,1) - bce(x,0) = -x  (fg correction)
        float tgt = (slab[m] == 0) ? pious : 0.f;
        lc += (double)bce_(oc.y, tgt);
        li += (double)(1.f - giou_(bx, sgb[m]));
        #pragma unroll
        for (int k = 0; k < 5; k++){
            float tx = slmk[m*10 + 2*k];
            float ty = slmk[m*10 + 2*k + 1];
            if (tx >= 0.f && ty >= 0.f){
                lnum += (double)(sl1_(lmkC[(size_t)(b*NA+pos)*10 + 2*k] - tx)
                               + sl1_(lmkC[(size_t)(b*NA+pos)*10 + 2*k + 1] - ty));
                lden += 1.0;
            }
        }
        nfg += 1.0;
    }

    __shared__ double s[6*256];
    s[0*256+tid] = lo; s[1*256+tid] = lc; s[2*256+tid] = li;
    s[3*256+tid] = lnum; s[4*256+tid] = lden; s[5*256+tid] = nfg;
    for (int off = 128; off >= 1; off >>= 1){
        __syncthreads();
        if (tid < off){
            #pragma unroll
            for (int q = 0; q < 6; q++) s[q*256+tid] += s[q*256+tid+off];
        }
    }
    if (tid == 0){
        #pragma unroll
        for (int q = 0; q < 6; q++) partials[(b*FGB + blockIdx.x)*6 + q] = s[q*256];
    }

    // ---- fused final combine: last of the 32 blocks does the reduction ----
    __threadfence();
    __shared__ int sLast;
    if (tid == 0) sLast = (atomicAdd(&ctr[CTR_FD], 1) == NB*FGB - 1);
    __syncthreads();
    if (!sLast) return;

    __shared__ double sf[NB][5];   // lo, lc, li, ll, nfg per image
    if (tid < NB){
        double flo = 0, flc = 0, fli = 0, fln = 0, fld = 0, fnf = 0;
        for (int ch = 0; ch < NCHUNK; ch++) flo += pObj[tid*NCHUNK + ch];
        for (int blk = 0; blk < FGB; blk++){
            const double* p = &partials[(tid*FGB + blk)*6];
            flo += p[0]; flc += p[1]; fli += p[2];
            fln += p[3]; fld += p[4]; fnf += p[5];
        }
        sf[tid][0] = flo; sf[tid][1] = flc; sf[tid][2] = fli;
        sf[tid][3] = fln / fmax(fld, 1.0); sf[tid][4] = fnf;
    }
    __syncthreads();
    if (tid == 0){
        double flo = 0, flc = 0, fli = 0, fll = 0, fnfg = 0;
        for (int bb = 0; bb < NB; bb++){
            flo += sf[bb][0]; flc += sf[bb][1]; fli += sf[bb][2]; fll += sf[bb][3]; fnfg += sf[bb][4];
        }
        double nf2 = fmax(fnfg, 1.0);
        double liou = 5.0 * fli / nf2;
        double lobj = 1.0 * flo / nf2;
        double lcls = 1.0 * flc / nf2;
        double llmk = 5.0 * fll / nf2;
        out[0] = (float)(liou + lobj + lcls + llmk);
        out[1] = (float)liou;
        out[2] = (float)lobj;
        out[3] = (float)lcls;
        out[4] = (float)llmk;
    }
}

extern "C" void kernel_launch(void* const* d_in, const int* in_sizes, int n_in,
                              void* d_out, int out_size, void* d_ws, size_t ws_size,
                              hipStream_t stream) {
    const float* cls0 = (const float*)d_in[0];
    const float* reg0 = (const float*)d_in[1];
    const float* obj0 = (const float*)d_in[2];
    const float* lmk0 = (const float*)d_in[3];
    const float* cls1 = (const float*)d_in[4];
    const float* reg1 = (const float*)d_in[5];
    const float* obj1 = (const float*)d_in[6];
    const float* lmk1 = (const float*)d_in[7];
    const float* cls2 = (const float*)d_in[8];
    const float* reg2 = (const float*)d_in[9];
    const float* obj2 = (const float*)d_in[10];
    const float* lmk2 = (const float*)d_in[11];
    const float* gtb  = (const float*)d_in[12];
    const float* gtlm = (const float*)d_in[13];
    const int*   gtl  = (const int*)d_in[14];
    const unsigned char* gtv_raw = (const unsigned char*)d_in[15];
    float* out = (float*)d_out;

    char* ws = (char*)d_ws;
    size_t off = 0;
    float4* boxC  = (float4*)(ws + off); off += (size_t)NB*NA*sizeof(float4);
    float4* metaC = (float4*)(ws + off); off += (size_t)NB*NA*sizeof(float4);
    int4* mstate  = (int4*)(ws + off);   off += (size_t)NB*NA*sizeof(int4);
    float* lmkC = (float*)(ws + off); off += (size_t)NB*NA*10*sizeof(float);
    float2* ocC = (float2*)(ws + off); off += (size_t)NB*NA*sizeof(float2);
    float* ccPC = (float*)(ws + off); off += (size_t)NB*NA*sizeof(float);
    float* ccNC = (float*)(ws + off); off += (size_t)NB*NA*sizeof(float);
    int* fgList = (int*)(ws + off);   off += (size_t)NB*NA*sizeof(int);
    int* posOf  = (int*)(ws + off);   off += (size_t)NB*NA*sizeof(int);
    int* mList  = (int*)(ws + off);   off += (size_t)NB*MCAP*sizeof(int);
    int* ctr    = (int*)(ws + off);   off += (size_t)8192;
    double* pObj = (double*)(ws + off); off += (size_t)NB*NCHUNK*sizeof(double);
    double* partials = (double*)(ws + off); off += (size_t)NB*FGB*6*sizeof(double);
    unsigned char* gtv = (unsigned char*)(ws + off); off += (size_t)NB*NG;

    hipMemsetAsync(ctr, 0, 8192, stream);

    dim3 grdA(NCHUNK, NB);
    k_decode<<<grdA, dim3(256), 0, stream>>>(cls0, reg0, obj0, lmk0, cls1, reg1, obj1, lmk1,
                                             cls2, reg2, obj2, lmk2, gtb, gtv_raw, gtv,
                                             fgList, posOf, ctr, boxC, metaC, ccPC, ccNC,
                                             lmkC, ocC, mstate, pObj);

    k_select<<<dim3(NB*NG), dim3(SELT), 0, stream>>>(fgList, posOf, ctr, boxC, metaC, ccPC, ccNC,
                                                     gtb, gtl, gtv, mstate, mList);

    k_fg_loss<<<dim3(FGB, NB), dim3(256), 0, stream>>>(boxC, metaC, ccPC, ccNC, lmkC, ocC,
                                                       posOf, mstate, mList, ctr,
                                                       gtb, gtlm, gtl, gtv, partials,
                                                       pObj, out);
}